// Round 7
// baseline (276.223 us; speedup 1.0000x reference)
//
#include <hip/hip_runtime.h>

#define B_ 32
#define T_ 12
#define F_ 4
#define L_ 1024
#define H_ 64
#define NROWS 1920   // 1536 x rows + 6*64 bias rows
#define NCH 256      // chunks (blocks); 4 links per chunk

typedef _Float16 f16x8 __attribute__((ext_vector_type(8)));
typedef float f32x4 __attribute__((ext_vector_type(4)));
typedef unsigned long long u64;

// XCD-chunked swizzle: XCD x owns chunks [32x, 32x+32) = links [128x, 128x+128)
__device__ __forceinline__ int chunk_of_block(int bid) {
    return ((bid & 7) << 5) + (bid >> 3);
}

// ---------------------------------------------------------------------------
// Prep: transpose x [1536 rows][L] and 6 bias arrays [64 rows][L] into
// params[l][NROWS], zero the edge counters.
// ---------------------------------------------------------------------------
__global__ __launch_bounds__(256) void prep(
    const float* __restrict__ x,
    const float* __restrict__ b_rh, const float* __restrict__ b_ri,
    const float* __restrict__ b_uh, const float* __restrict__ b_ui,
    const float* __restrict__ b_nh, const float* __restrict__ b_ni,
    float* __restrict__ params, int* __restrict__ cnt)
{
    const int tid = threadIdx.x;
    const int rt  = blockIdx.x >> 4;   // 30 row tiles
    const int lt  = blockIdx.x & 15;   // 16 link tiles
    __shared__ float lds[64][65];

    if (blockIdx.x == 0 && tid < NCH) {
        __hip_atomic_store(&cnt[tid], 0, __ATOMIC_RELAXED, __HIP_MEMORY_SCOPE_AGENT);
        __hip_atomic_store(&cnt[NCH + tid], 0, __ATOMIC_RELAXED, __HIP_MEMORY_SCOPE_AGENT);
    }

    #pragma unroll
    for (int i = 0; i < 16; ++i) {
        const int e  = i * 256 + tid;
        const int rl = e >> 6, ll = e & 63;
        const int r  = rt * 64 + rl, l = lt * 64 + ll;
        float v;
        if (r < 1536) {
            v = x[(size_t)r * L_ + l];
        } else {
            const int rb = r - 1536;
            const int g  = rb >> 6;
            const float* bp = (g == 0) ? b_rh : (g == 1) ? b_ri : (g == 2) ? b_uh
                            : (g == 3) ? b_ui : (g == 4) ? b_nh : b_ni;
            v = bp[(size_t)(rb & 63) * L_ + l];
        }
        lds[rl][ll] = v;
    }
    __syncthreads();
    #pragma unroll
    for (int i = 0; i < 16; ++i) {
        const int e  = i * 256 + tid;
        const int ll = e >> 6, rl = e & 63;
        params[(size_t)(lt * 64 + ll) * NROWS + rt * 64 + rl] = lds[rl][ll];
    }
}

// ---------------------------------------------------------------------------
// Prep_w: pack all per-link MFMA B fragments (fp16) in consumer-coalesced
// layout Wpk[l][f][lane], f = nt*9 + s with s: 0,1=r ks0/1, 2=r x, 3,4=z ks,
// 5=z x, 6,7=nh ks, 8=nx x. x-frags occupy K rows 0..3 of a K=32 step.
// ---------------------------------------------------------------------------
__global__ __launch_bounds__(256) void prep_w(
    const float* __restrict__ w_rh, const float* __restrict__ w_uh,
    const float* __restrict__ w_nh,
    const float* __restrict__ w_ri, const float* __restrict__ w_ui,
    const float* __restrict__ w_ni, _Float16* __restrict__ Wpk)
{
    const int l  = blockIdx.x;
    const int fq = threadIdx.x >> 6, m = threadIdx.x & 63;
    const int n  = m & 15, kq = m >> 4;
    #pragma unroll
    for (int i = 0; i < 9; ++i) {
        const int f  = i * 4 + fq;          // 0..35
        const int nt = f / 9, s = f % 9;
        const int grp = s / 3, sub = s % 3; // grp 0=r,1=z,2=n
        f16x8 v;
        if (sub < 2) {   // hidden-weight fragment, ks = sub
            const float* wh = (grp == 0) ? w_rh : (grp == 1) ? w_uh : w_nh;
            #pragma unroll
            for (int j = 0; j < 8; ++j)
                v[j] = (_Float16)wh[(size_t)l * 4096
                         + (size_t)(sub * 32 + kq * 8 + j) * 64 + nt * 16 + n];
        } else {         // x-weight fragment (K=32, rows 0..3 live)
            const float* wx = (grp == 0) ? w_ri : (grp == 1) ? w_ui : w_ni;
            #pragma unroll
            for (int j = 0; j < 8; ++j) {
                const int k = kq * 8 + j;
                v[j] = (k < 4) ? (_Float16)wx[(size_t)l * 256 + k * 64 + nt * 16 + n]
                               : (_Float16)0.0f;
            }
        }
        *(f16x8*)(Wpk + (((size_t)l * 36 + f) * 64 + m) * 8) = v;
    }
}

// LDS h buffer: [parity][link 0..3][b 0..31][k 0..63] fp16, XOR-swizzled rows
__device__ __forceinline__ int h_byte(int p, int w, int b, int k) {
    int byte = ((((p * 4 + w) * 32 + b) * 64) + k) * 2;
    return byte ^ ((b & 7) << 4);
}

// ---------------------------------------------------------------------------
// Persistent GRU: 256 blocks (1/CU) x 512 threads (8 waves = 2/SIMD).
// Wave w: link lw = w>>1 of the chunk, batch-half mt = w&1.
// Weights in registers; interior neighbor h via LDS; chunk-edge h via
// agent-scope atomic u64 halos with per-side RELEASE counters. Only the 4
// edge waves ever poll; interior waves only hit the per-step block barrier.
// ---------------------------------------------------------------------------
__global__ __launch_bounds__(512, 2) void gru_persist(
    const _Float16* __restrict__ Wpk,
    const float* __restrict__ att,  const float* __restrict__ params,
    const float* __restrict__ w_fc, const float* __restrict__ b_fc,
    _Float16* __restrict__ gh, int* __restrict__ cnt,
    float* __restrict__ out)
{
    const int c    = chunk_of_block(blockIdx.x);
    const int tid  = threadIdx.x;
    const int w    = tid >> 6, lane = tid & 63;
    const int n    = lane & 15, kq = lane >> 4;
    const int lw   = w >> 1, mt = w & 1;
    const int l    = c * 4 + lw;

    __shared__ __align__(16) _Float16 hbuf[2 * 4 * 32 * 64];  // 32 KB
    __shared__ __align__(16) float    xs[4][1536];            // 24 KB

    // ---- stage this link's x into LDS (wave-pair cooperative, coalesced)
    const float* prow = params + (size_t)l * NROWS;
    {
        const float4* src = (const float4*)prow;
        float4* dst = (float4*)xs[lw];
        const int sub = tid & 127;     // position within the wave pair
        #pragma unroll
        for (int i = 0; i < 3; ++i) dst[sub + i * 128] = src[sub + i * 128];
    }

    // ---- per-lane persistent constants (all coalesced: 1 KB / instruction)
    f16x8 bw[36];
    {
        const f16x8* wp = (const f16x8*)Wpk + (size_t)l * 36 * 64;
        #pragma unroll
        for (int f = 0; f < 36; ++f) bw[f] = wp[f * 64 + lane];
    }
    float brv[4], bzv[4], bnhv[4], bniv[4], wfcv[4];
    #pragma unroll
    for (int nt = 0; nt < 4; ++nt) {
        const int ko = nt * 16 + n;
        brv[nt]  = prow[1536 + 0 * 64 + ko] + prow[1536 + 1 * 64 + ko];
        bzv[nt]  = prow[1536 + 2 * 64 + ko] + prow[1536 + 3 * 64 + ko];
        bnhv[nt] = prow[1536 + 4 * 64 + ko];
        bniv[nt] = prow[1536 + 5 * 64 + ko];
        wfcv[nt] = w_fc[(size_t)l * H_ + ko];
    }
    const _Float16 ach = (_Float16)att[(size_t)l * L_ + l];
    const _Float16 alh = (l > 0)      ? (_Float16)att[(size_t)l * L_ + l - 1] : (_Float16)0.0f;
    const _Float16 arh = (l < L_ - 1) ? (_Float16)att[(size_t)l * L_ + l + 1] : (_Float16)0.0f;

    __syncthreads();   // xs ready

    float hvv[4][4] = {};   // [nt][r] running hidden state (this wave's b-half)

    #pragma unroll 1
    for (int t = 0; t < T_; ++t) {
        f32x4 ar[4] = {}, az[4] = {}, anh[4] = {}, anx[4] = {};
        if (t > 0) {
            // only edge waves poll; RELAXED (coherent-point) + control dep
            if (lw == 0 && c > 0)
                while (__hip_atomic_load(&cnt[NCH + c - 1], __ATOMIC_RELAXED,
                                         __HIP_MEMORY_SCOPE_AGENT) < 2 * t)
                    __builtin_amdgcn_s_sleep(1);
            if (lw == 3 && c < NCH - 1)
                while (__hip_atomic_load(&cnt[c + 1], __ATOMIC_RELAXED,
                                         __HIP_MEMORY_SCOPE_AGENT) < 2 * t)
                    __builtin_amdgcn_s_sleep(1);

            const int p = (t - 1) & 1;
            const char* hb = (const char*)hbuf;
            f16x8 af[2];
            #pragma unroll
            for (int ks = 0; ks < 2; ++ks) {
                const int b  = mt * 16 + n;
                const int k0 = ks * 32 + kq * 8;
                const f16x8 hs = *(const f16x8*)(hb + h_byte(p, lw, b, k0));
                f16x8 hl, hr;
                if (lw > 0) {
                    hl = *(const f16x8*)(hb + h_byte(p, lw - 1, b, k0));
                } else if (c > 0) {
                    const u64* s64 = (const u64*)(gh +
                        ((((size_t)p * NCH + (c - 1)) * 2 + 1) * 2048));
                    union { u64 uu[2]; f16x8 v; } cv;
                    cv.uu[0] = __hip_atomic_load(s64 + b * 16 + (k0 >> 2),
                                 __ATOMIC_RELAXED, __HIP_MEMORY_SCOPE_AGENT);
                    cv.uu[1] = __hip_atomic_load(s64 + b * 16 + (k0 >> 2) + 1,
                                 __ATOMIC_RELAXED, __HIP_MEMORY_SCOPE_AGENT);
                    hl = cv.v;
                } else {
                    hl = hs;   // a_l == 0
                }
                if (lw < 3) {
                    hr = *(const f16x8*)(hb + h_byte(p, lw + 1, b, k0));
                } else if (c < NCH - 1) {
                    const u64* s64 = (const u64*)(gh +
                        ((((size_t)p * NCH + (c + 1)) * 2 + 0) * 2048));
                    union { u64 uu[2]; f16x8 v; } cv;
                    cv.uu[0] = __hip_atomic_load(s64 + b * 16 + (k0 >> 2),
                                 __ATOMIC_RELAXED, __HIP_MEMORY_SCOPE_AGENT);
                    cv.uu[1] = __hip_atomic_load(s64 + b * 16 + (k0 >> 2) + 1,
                                 __ATOMIC_RELAXED, __HIP_MEMORY_SCOPE_AGENT);
                    hr = cv.v;
                } else {
                    hr = hs;   // a_r == 0
                }
                af[ks] = ach * hs + alh * hl + arh * hr;   // packed f16 FMA
            }
            #pragma unroll
            for (int nt = 0; nt < 4; ++nt) {
                ar[nt]  = __builtin_amdgcn_mfma_f32_16x16x32_f16(af[0], bw[nt*9+0], ar[nt],  0,0,0);
                ar[nt]  = __builtin_amdgcn_mfma_f32_16x16x32_f16(af[1], bw[nt*9+1], ar[nt],  0,0,0);
                az[nt]  = __builtin_amdgcn_mfma_f32_16x16x32_f16(af[0], bw[nt*9+3], az[nt],  0,0,0);
                az[nt]  = __builtin_amdgcn_mfma_f32_16x16x32_f16(af[1], bw[nt*9+4], az[nt],  0,0,0);
                anh[nt] = __builtin_amdgcn_mfma_f32_16x16x32_f16(af[0], bw[nt*9+6], anh[nt], 0,0,0);
                anh[nt] = __builtin_amdgcn_mfma_f32_16x16x32_f16(af[1], bw[nt*9+7], anh[nt], 0,0,0);
            }
        }

        // ---- x contribution via MFMA (K rows 0..3 of a K=32 step)
        {
            f16x8 ax = {};
            if (kq == 0) {
                const int b = mt * 16 + n;
                const float4 xb = *(const float4*)&xs[lw][b * 48 + t * 4];
                ax[0] = (_Float16)xb.x; ax[1] = (_Float16)xb.y;
                ax[2] = (_Float16)xb.z; ax[3] = (_Float16)xb.w;
            }
            #pragma unroll
            for (int nt = 0; nt < 4; ++nt) {
                ar[nt]  = __builtin_amdgcn_mfma_f32_16x16x32_f16(ax, bw[nt*9+2], ar[nt],  0,0,0);
                az[nt]  = __builtin_amdgcn_mfma_f32_16x16x32_f16(ax, bw[nt*9+5], az[nt],  0,0,0);
                anx[nt] = __builtin_amdgcn_mfma_f32_16x16x32_f16(ax, bw[nt*9+8], anx[nt], 0,0,0);
            }
        }

        // ---- gates + state update (f32)
        #pragma unroll
        for (int nt = 0; nt < 4; ++nt) {
            #pragma unroll
            for (int r = 0; r < 4; ++r) {
                const float pre_r = ar[nt][r] + brv[nt];
                const float pre_z = az[nt][r] + bzv[nt];
                const float rg = 1.0f / (1.0f + __expf(-pre_r));
                const float zg = 1.0f / (1.0f + __expf(-pre_z));
                float npre = anx[nt][r] + bniv[nt] + rg * (anh[nt][r] + bnhv[nt]);
                npre = fminf(fmaxf(npre, -15.0f), 15.0f);
                const float e2 = __expf(2.0f * npre);
                const float nn = (e2 - 1.0f) / (e2 + 1.0f);
                hvv[nt][r] = (1.0f - zg) * nn + zg * hvv[nt][r];
            }
        }

        if (t < T_ - 1) {
            const int q = t & 1;
            char* hb = (char*)hbuf;
            #pragma unroll
            for (int nt = 0; nt < 4; ++nt)
                #pragma unroll
                for (int r = 0; r < 4; ++r)
                    *(_Float16*)(hb + h_byte(q, lw, mt * 16 + kq * 4 + r, nt * 16 + n))
                        = (_Float16)hvv[nt][r];
            // edge waves: push this link's b-half halo + RELEASE counter bump
            // (release fetch_add drains vmcnt first => halo stores visible)
            if (lw == 0 && c > 0) {
                u64* ge = (u64*)(gh + (((size_t)q * NCH + c) * 2 + 0) * 2048);
                #pragma unroll
                for (int i = 0; i < 4; ++i) {
                    const int idx = mt * 256 + lane + i * 64;   // u64 idx = b*16+kk
                    const u64 v = *(const u64*)(hb + h_byte(q, 0, idx >> 4, (idx & 15) * 4));
                    __hip_atomic_store(ge + idx, v, __ATOMIC_RELAXED,
                                       __HIP_MEMORY_SCOPE_AGENT);
                }
                if (lane == 0)
                    __hip_atomic_fetch_add(&cnt[c], 1, __ATOMIC_RELEASE,
                                           __HIP_MEMORY_SCOPE_AGENT);
            }
            if (lw == 3 && c < NCH - 1) {
                u64* ge = (u64*)(gh + (((size_t)q * NCH + c) * 2 + 1) * 2048);
                #pragma unroll
                for (int i = 0; i < 4; ++i) {
                    const int idx = mt * 256 + lane + i * 64;
                    const u64 v = *(const u64*)(hb + h_byte(q, 3, idx >> 4, (idx & 15) * 4));
                    __hip_atomic_store(ge + idx, v, __ATOMIC_RELAXED,
                                       __HIP_MEMORY_SCOPE_AGENT);
                }
                if (lane == 0)
                    __hip_atomic_fetch_add(&cnt[NCH + c], 1, __ATOMIC_RELEASE,
                                           __HIP_MEMORY_SCOPE_AGENT);
            }
            __syncthreads();   // hbuf parity q visible to sibling waves
        } else {
            // FC head: each wave owns disjoint (b,l) -> no cross-wave reduce
            #pragma unroll
            for (int r = 0; r < 4; ++r) {
                float s = hvv[0][r] * wfcv[0] + hvv[1][r] * wfcv[1]
                        + hvv[2][r] * wfcv[2] + hvv[3][r] * wfcv[3];
                s += __shfl_xor(s, 1, 64);
                s += __shfl_xor(s, 2, 64);
                s += __shfl_xor(s, 4, 64);
                s += __shfl_xor(s, 8, 64);
                if (n == 0)
                    out[(size_t)(mt * 16 + kq * 4 + r) * L_ + l] = s + b_fc[l];
            }
        }
    }
}

extern "C" void kernel_launch(void* const* d_in, const int* in_sizes, int n_in,
                              void* d_out, int out_size, void* d_ws, size_t ws_size,
                              hipStream_t stream) {
    const float* x    = (const float*)d_in[0];
    const float* att  = (const float*)d_in[1];
    const float* w_rh = (const float*)d_in[2];
    const float* b_rh = (const float*)d_in[3];
    const float* w_ri = (const float*)d_in[4];
    const float* b_ri = (const float*)d_in[5];
    const float* w_uh = (const float*)d_in[6];
    const float* b_uh = (const float*)d_in[7];
    const float* w_ui = (const float*)d_in[8];
    const float* b_ui = (const float*)d_in[9];
    const float* w_nh = (const float*)d_in[10];
    const float* b_nh = (const float*)d_in[11];
    const float* w_ni = (const float*)d_in[12];
    const float* b_ni = (const float*)d_in[13];
    const float* w_fc = (const float*)d_in[14];
    const float* b_fc = (const float*)d_in[15];
    float* out = (float*)d_out;

    char* ws = (char*)d_ws;
    float*    params = (float*)ws;                     // 7.9 MB
    _Float16* gh     = (_Float16*)(ws + (8u << 20));   // 4 MB edge halos
    int*      cnt    = (int*)(ws + (12u << 20));       // 2 KB counters
    _Float16* Wpk    = (_Float16*)(ws + (13u << 20));  // 36 MB packed weights

    prep<<<480, 256, 0, stream>>>(x, b_rh, b_ri, b_uh, b_ui, b_nh, b_ni,
                                  params, cnt);
    prep_w<<<L_, 256, 0, stream>>>(w_rh, w_uh, w_nh, w_ri, w_ui, w_ni, Wpk);

    void* args[] = {
        (void*)&Wpk, (void*)&att, (void*)&params, (void*)&w_fc, (void*)&b_fc,
        (void*)&gh,  (void*)&cnt, (void*)&out,
    };
    hipError_t e = hipLaunchCooperativeKernel((const void*)gru_persist,
                                              dim3(NCH), dim3(512), args, 0, stream);
    if (e != hipSuccess) {
        // 256 blocks at 1 block/CU on 256 CUs: co-resident regardless.
        gru_persist<<<NCH, 512, 0, stream>>>(Wpk, att, params, w_fc, b_fc,
                                             gh, cnt, out);
    }
}

// Round 8
// 230.316 us; speedup vs baseline: 1.1993x; 1.1993x over previous
//
#include <hip/hip_runtime.h>

#define B_ 32
#define T_ 12
#define F_ 4
#define L_ 1024
#define H_ 64
#define NROWS 1920   // 1536 x rows + 6*64 bias rows
#define NCH 256      // chunks (blocks); 4 links per chunk

typedef _Float16 f16x8 __attribute__((ext_vector_type(8)));
typedef float f32x4 __attribute__((ext_vector_type(4)));
typedef unsigned long long u64;

// XCD-chunked swizzle: XCD x owns chunks [32x, 32x+32) = links [128x, 128x+128)
__device__ __forceinline__ int chunk_of_block(int bid) {
    return ((bid & 7) << 5) + (bid >> 3);
}

// ---------------------------------------------------------------------------
// Prep: transpose x [1536 rows][L] and 6 bias arrays [64 rows][L] into
// params[l][NROWS], zero the edge counters.
// ---------------------------------------------------------------------------
__global__ __launch_bounds__(256) void prep(
    const float* __restrict__ x,
    const float* __restrict__ b_rh, const float* __restrict__ b_ri,
    const float* __restrict__ b_uh, const float* __restrict__ b_ui,
    const float* __restrict__ b_nh, const float* __restrict__ b_ni,
    float* __restrict__ params, int* __restrict__ cnt)
{
    const int tid = threadIdx.x;
    const int rt  = blockIdx.x >> 4;   // 30 row tiles
    const int lt  = blockIdx.x & 15;   // 16 link tiles
    __shared__ float lds[64][65];

    if (blockIdx.x == 0 && tid < NCH) {
        __hip_atomic_store(&cnt[tid], 0, __ATOMIC_RELAXED, __HIP_MEMORY_SCOPE_AGENT);
        __hip_atomic_store(&cnt[NCH + tid], 0, __ATOMIC_RELAXED, __HIP_MEMORY_SCOPE_AGENT);
    }

    #pragma unroll
    for (int i = 0; i < 16; ++i) {
        const int e  = i * 256 + tid;
        const int rl = e >> 6, ll = e & 63;
        const int r  = rt * 64 + rl, l = lt * 64 + ll;
        float v;
        if (r < 1536) {
            v = x[(size_t)r * L_ + l];
        } else {
            const int rb = r - 1536;
            const int g  = rb >> 6;
            const float* bp = (g == 0) ? b_rh : (g == 1) ? b_ri : (g == 2) ? b_uh
                            : (g == 3) ? b_ui : (g == 4) ? b_nh : b_ni;
            v = bp[(size_t)(rb & 63) * L_ + l];
        }
        lds[rl][ll] = v;
    }
    __syncthreads();
    #pragma unroll
    for (int i = 0; i < 16; ++i) {
        const int e  = i * 256 + tid;
        const int ll = e >> 6, rl = e & 63;
        params[(size_t)(lt * 64 + ll) * NROWS + rt * 64 + rl] = lds[rl][ll];
    }
}

// ---------------------------------------------------------------------------
// Prep_w: pack all per-link MFMA B fragments (fp16) in consumer-coalesced
// layout Wpk[l][f][lane], f = nt*9 + s with s: 0,1=r ks0/1, 2=r x, 3,4=z ks,
// 5=z x, 6,7=nh ks, 8=nx x. x-frags occupy K rows 0..3 of a K=32 step.
// ---------------------------------------------------------------------------
__global__ __launch_bounds__(256) void prep_w(
    const float* __restrict__ w_rh, const float* __restrict__ w_uh,
    const float* __restrict__ w_nh,
    const float* __restrict__ w_ri, const float* __restrict__ w_ui,
    const float* __restrict__ w_ni, _Float16* __restrict__ Wpk)
{
    const int l  = blockIdx.x;
    const int fq = threadIdx.x >> 6, m = threadIdx.x & 63;
    const int n  = m & 15, kq = m >> 4;
    #pragma unroll
    for (int i = 0; i < 9; ++i) {
        const int f  = i * 4 + fq;          // 0..35
        const int nt = f / 9, s = f % 9;
        const int grp = s / 3, sub = s % 3; // grp 0=r,1=z,2=n
        f16x8 v;
        if (sub < 2) {   // hidden-weight fragment, ks = sub
            const float* wh = (grp == 0) ? w_rh : (grp == 1) ? w_uh : w_nh;
            #pragma unroll
            for (int j = 0; j < 8; ++j)
                v[j] = (_Float16)wh[(size_t)l * 4096
                         + (size_t)(sub * 32 + kq * 8 + j) * 64 + nt * 16 + n];
        } else {         // x-weight fragment (K=32, rows 0..3 live)
            const float* wx = (grp == 0) ? w_ri : (grp == 1) ? w_ui : w_ni;
            #pragma unroll
            for (int j = 0; j < 8; ++j) {
                const int k = kq * 8 + j;
                v[j] = (k < 4) ? (_Float16)wx[(size_t)l * 256 + k * 64 + nt * 16 + n]
                               : (_Float16)0.0f;
            }
        }
        *(f16x8*)(Wpk + (((size_t)l * 36 + f) * 64 + m) * 8) = v;
    }
}

// LDS h buffer: [parity][link 0..3][b 0..31][k 0..63] fp16, XOR-swizzled rows
__device__ __forceinline__ int h_byte(int p, int w, int b, int k) {
    int byte = ((((p * 4 + w) * 32 + b) * 64) + k) * 2;
    return byte ^ ((b & 7) << 4);
}

// ---------------------------------------------------------------------------
// Persistent GRU: 256 blocks (1/CU) x 512 threads (8 waves = 2/SIMD).
// Wave w: link lw = w>>1, output-half nth = w&1 (k columns nth*32..+32).
// nt-split => the two waves of a link hold DISJOINT weight fragments
// (18 each = 72 VGPRs), keeping the wave under the 256-VGPR 2-wave/SIMD cap.
// Interior neighbor h via LDS; chunk-edge h via agent-scope atomic u64 halos
// with per-side RELEASE counters (2 bumps/step/side, one per nth wave).
// ---------------------------------------------------------------------------
__global__ __launch_bounds__(512, 1) void gru_persist(
    const _Float16* __restrict__ Wpk,
    const float* __restrict__ att,  const float* __restrict__ params,
    const float* __restrict__ w_fc, const float* __restrict__ b_fc,
    _Float16* __restrict__ gh, int* __restrict__ cnt,
    float* __restrict__ out)
{
    const int c    = chunk_of_block(blockIdx.x);
    const int tid  = threadIdx.x;
    const int w    = tid >> 6, lane = tid & 63;
    const int n    = lane & 15, kq = lane >> 4;
    const int lw   = w >> 1, nth = w & 1;
    const int l    = c * 4 + lw;

    __shared__ __align__(16) _Float16 hbuf[2 * 4 * 32 * 64];  // 32 KB
    __shared__ __align__(16) float    xs[4][1536];            // 24 KB
    __shared__ float psum[4][2][B_];                          // 1 KB (FC head)

    // ---- stage this link's x into LDS (wave-pair cooperative, coalesced)
    const float* prow = params + (size_t)l * NROWS;
    {
        const float4* src = (const float4*)prow;
        float4* dst = (float4*)xs[lw];
        const int sub = tid & 127;     // position within the wave pair
        #pragma unroll
        for (int i = 0; i < 3; ++i) dst[sub + i * 128] = src[sub + i * 128];
    }

    // ---- per-lane persistent constants (disjoint per nth; all coalesced)
    f16x8 bw[2][9];   // [q = local nt][s]
    {
        const f16x8* wp = (const f16x8*)Wpk + (size_t)l * 36 * 64;
        #pragma unroll
        for (int q = 0; q < 2; ++q)
            #pragma unroll
            for (int s = 0; s < 9; ++s)
                bw[q][s] = wp[((nth * 2 + q) * 9 + s) * 64 + lane];
    }
    float brv[2], bzv[2], bnhv[2], bniv[2], wfcv[2];
    #pragma unroll
    for (int q = 0; q < 2; ++q) {
        const int ko = (nth * 2 + q) * 16 + n;
        brv[q]  = prow[1536 + 0 * 64 + ko] + prow[1536 + 1 * 64 + ko];
        bzv[q]  = prow[1536 + 2 * 64 + ko] + prow[1536 + 3 * 64 + ko];
        bnhv[q] = prow[1536 + 4 * 64 + ko];
        bniv[q] = prow[1536 + 5 * 64 + ko];
        wfcv[q] = w_fc[(size_t)l * H_ + ko];
    }
    const _Float16 ach = (_Float16)att[(size_t)l * L_ + l];
    const _Float16 alh = (l > 0)      ? (_Float16)att[(size_t)l * L_ + l - 1] : (_Float16)0.0f;
    const _Float16 arh = (l < L_ - 1) ? (_Float16)att[(size_t)l * L_ + l + 1] : (_Float16)0.0f;

    __syncthreads();   // xs ready

    float hvv[2][2][4] = {};   // [mt][q][r]

    #pragma unroll 1
    for (int t = 0; t < T_; ++t) {
        f32x4 ar[2][2] = {}, az[2][2] = {}, anh[2][2] = {}, anx[2][2] = {};
        if (t > 0) {
            // only edge-link waves poll; RELAXED (coherent-point) + control dep
            if (lw == 0 && c > 0)
                while (__hip_atomic_load(&cnt[NCH + c - 1], __ATOMIC_RELAXED,
                                         __HIP_MEMORY_SCOPE_AGENT) < 2 * t)
                    __builtin_amdgcn_s_sleep(1);
            if (lw == 3 && c < NCH - 1)
                while (__hip_atomic_load(&cnt[c + 1], __ATOMIC_RELAXED,
                                         __HIP_MEMORY_SCOPE_AGENT) < 2 * t)
                    __builtin_amdgcn_s_sleep(1);

            const int p = (t - 1) & 1;
            const char* hb = (const char*)hbuf;
            f16x8 af[2][2];   // [mt][ks], full k range
            #pragma unroll
            for (int mt = 0; mt < 2; ++mt) {
                #pragma unroll
                for (int ks = 0; ks < 2; ++ks) {
                    const int b  = mt * 16 + n;
                    const int k0 = ks * 32 + kq * 8;
                    const f16x8 hs = *(const f16x8*)(hb + h_byte(p, lw, b, k0));
                    f16x8 hl, hr;
                    if (lw > 0) {
                        hl = *(const f16x8*)(hb + h_byte(p, lw - 1, b, k0));
                    } else if (c > 0) {
                        const u64* s64 = (const u64*)(gh +
                            ((((size_t)p * NCH + (c - 1)) * 2 + 1) * 2048));
                        union { u64 uu[2]; f16x8 v; } cv;
                        cv.uu[0] = __hip_atomic_load(s64 + b * 16 + (k0 >> 2),
                                     __ATOMIC_RELAXED, __HIP_MEMORY_SCOPE_AGENT);
                        cv.uu[1] = __hip_atomic_load(s64 + b * 16 + (k0 >> 2) + 1,
                                     __ATOMIC_RELAXED, __HIP_MEMORY_SCOPE_AGENT);
                        hl = cv.v;
                    } else {
                        hl = hs;   // a_l == 0
                    }
                    if (lw < 3) {
                        hr = *(const f16x8*)(hb + h_byte(p, lw + 1, b, k0));
                    } else if (c < NCH - 1) {
                        const u64* s64 = (const u64*)(gh +
                            ((((size_t)p * NCH + (c + 1)) * 2 + 0) * 2048));
                        union { u64 uu[2]; f16x8 v; } cv;
                        cv.uu[0] = __hip_atomic_load(s64 + b * 16 + (k0 >> 2),
                                     __ATOMIC_RELAXED, __HIP_MEMORY_SCOPE_AGENT);
                        cv.uu[1] = __hip_atomic_load(s64 + b * 16 + (k0 >> 2) + 1,
                                     __ATOMIC_RELAXED, __HIP_MEMORY_SCOPE_AGENT);
                        hr = cv.v;
                    } else {
                        hr = hs;   // a_r == 0
                    }
                    af[mt][ks] = ach * hs + alh * hl + arh * hr;   // packed f16 FMA
                }
            }
            #pragma unroll
            for (int q = 0; q < 2; ++q)
                #pragma unroll
                for (int mt = 0; mt < 2; ++mt) {
                    ar[mt][q]  = __builtin_amdgcn_mfma_f32_16x16x32_f16(af[mt][0], bw[q][0], ar[mt][q],  0,0,0);
                    ar[mt][q]  = __builtin_amdgcn_mfma_f32_16x16x32_f16(af[mt][1], bw[q][1], ar[mt][q],  0,0,0);
                    az[mt][q]  = __builtin_amdgcn_mfma_f32_16x16x32_f16(af[mt][0], bw[q][3], az[mt][q],  0,0,0);
                    az[mt][q]  = __builtin_amdgcn_mfma_f32_16x16x32_f16(af[mt][1], bw[q][4], az[mt][q],  0,0,0);
                    anh[mt][q] = __builtin_amdgcn_mfma_f32_16x16x32_f16(af[mt][0], bw[q][6], anh[mt][q], 0,0,0);
                    anh[mt][q] = __builtin_amdgcn_mfma_f32_16x16x32_f16(af[mt][1], bw[q][7], anh[mt][q], 0,0,0);
                }
        }

        // ---- x contribution via MFMA (K rows 0..3 of a K=32 step)
        {
            f16x8 ax[2] = {};
            #pragma unroll
            for (int mt = 0; mt < 2; ++mt)
                if (kq == 0) {
                    const float4 xb = *(const float4*)&xs[lw][(mt * 16 + n) * 48 + t * 4];
                    ax[mt][0] = (_Float16)xb.x; ax[mt][1] = (_Float16)xb.y;
                    ax[mt][2] = (_Float16)xb.z; ax[mt][3] = (_Float16)xb.w;
                }
            #pragma unroll
            for (int q = 0; q < 2; ++q)
                #pragma unroll
                for (int mt = 0; mt < 2; ++mt) {
                    ar[mt][q]  = __builtin_amdgcn_mfma_f32_16x16x32_f16(ax[mt], bw[q][2], ar[mt][q],  0,0,0);
                    az[mt][q]  = __builtin_amdgcn_mfma_f32_16x16x32_f16(ax[mt], bw[q][5], az[mt][q],  0,0,0);
                    anx[mt][q] = __builtin_amdgcn_mfma_f32_16x16x32_f16(ax[mt], bw[q][8], anx[mt][q], 0,0,0);
                }
        }

        // ---- gates + state update (f32)
        #pragma unroll
        for (int mt = 0; mt < 2; ++mt)
            #pragma unroll
            for (int q = 0; q < 2; ++q)
                #pragma unroll
                for (int r = 0; r < 4; ++r) {
                    const float pre_r = ar[mt][q][r] + brv[q];
                    const float pre_z = az[mt][q][r] + bzv[q];
                    const float rg = 1.0f / (1.0f + __expf(-pre_r));
                    const float zg = 1.0f / (1.0f + __expf(-pre_z));
                    float npre = anx[mt][q][r] + bniv[q] + rg * (anh[mt][q][r] + bnhv[q]);
                    npre = fminf(fmaxf(npre, -15.0f), 15.0f);
                    const float e2 = __expf(2.0f * npre);
                    const float nn = (e2 - 1.0f) / (e2 + 1.0f);
                    hvv[mt][q][r] = (1.0f - zg) * nn + zg * hvv[mt][q][r];
                }

        if (t < T_ - 1) {
            const int qp = t & 1;
            char* hb = (char*)hbuf;
            #pragma unroll
            for (int mt = 0; mt < 2; ++mt)
                #pragma unroll
                for (int q = 0; q < 2; ++q)
                    #pragma unroll
                    for (int r = 0; r < 4; ++r)
                        *(_Float16*)(hb + h_byte(qp, lw, mt * 16 + kq * 4 + r,
                                                 (nth * 2 + q) * 16 + n))
                            = (_Float16)hvv[mt][q][r];
            // edge waves: push own k-half halo (all b) + RELEASE counter bump
            if (lw == 0 && c > 0) {
                u64* ge = (u64*)(gh + (((size_t)qp * NCH + c) * 2 + 0) * 2048);
                #pragma unroll
                for (int i = 0; i < 4; ++i) {
                    const int idx2 = lane + i * 64;          // 0..255
                    const int b = idx2 >> 3, kk = idx2 & 7;  // k-half: 8 u64 per b
                    const u64 v = *(const u64*)(hb + h_byte(qp, 0, b, nth * 32 + kk * 4));
                    __hip_atomic_store(ge + b * 16 + nth * 8 + kk, v,
                                       __ATOMIC_RELAXED, __HIP_MEMORY_SCOPE_AGENT);
                }
                if (lane == 0)
                    __hip_atomic_fetch_add(&cnt[c], 1, __ATOMIC_RELEASE,
                                           __HIP_MEMORY_SCOPE_AGENT);
            }
            if (lw == 3 && c < NCH - 1) {
                u64* ge = (u64*)(gh + (((size_t)qp * NCH + c) * 2 + 1) * 2048);
                #pragma unroll
                for (int i = 0; i < 4; ++i) {
                    const int idx2 = lane + i * 64;
                    const int b = idx2 >> 3, kk = idx2 & 7;
                    const u64 v = *(const u64*)(hb + h_byte(qp, 3, b, nth * 32 + kk * 4));
                    __hip_atomic_store(ge + b * 16 + nth * 8 + kk, v,
                                       __ATOMIC_RELAXED, __HIP_MEMORY_SCOPE_AGENT);
                }
                if (lane == 0)
                    __hip_atomic_fetch_add(&cnt[NCH + c], 1, __ATOMIC_RELEASE,
                                           __HIP_MEMORY_SCOPE_AGENT);
            }
            __syncthreads();   // hbuf parity qp visible to sibling waves
        } else {
            // FC head: partial over own k-half, combine nth pair via LDS
            #pragma unroll
            for (int mt = 0; mt < 2; ++mt)
                #pragma unroll
                for (int r = 0; r < 4; ++r) {
                    float s = hvv[mt][0][r] * wfcv[0] + hvv[mt][1][r] * wfcv[1];
                    s += __shfl_xor(s, 1, 64);
                    s += __shfl_xor(s, 2, 64);
                    s += __shfl_xor(s, 4, 64);
                    s += __shfl_xor(s, 8, 64);
                    if (n == 0) psum[lw][nth][mt * 16 + kq * 4 + r] = s;
                }
            __syncthreads();
            if (tid < 128) {
                const int lw2 = tid >> 5, b = tid & 31;
                const int l2 = c * 4 + lw2;
                out[(size_t)b * L_ + l2] =
                    psum[lw2][0][b] + psum[lw2][1][b] + b_fc[l2];
            }
        }
    }
}

extern "C" void kernel_launch(void* const* d_in, const int* in_sizes, int n_in,
                              void* d_out, int out_size, void* d_ws, size_t ws_size,
                              hipStream_t stream) {
    const float* x    = (const float*)d_in[0];
    const float* att  = (const float*)d_in[1];
    const float* w_rh = (const float*)d_in[2];
    const float* b_rh = (const float*)d_in[3];
    const float* w_ri = (const float*)d_in[4];
    const float* b_ri = (const float*)d_in[5];
    const float* w_uh = (const float*)d_in[6];
    const float* b_uh = (const float*)d_in[7];
    const float* w_ui = (const float*)d_in[8];
    const float* b_ui = (const float*)d_in[9];
    const float* w_nh = (const float*)d_in[10];
    const float* b_nh = (const float*)d_in[11];
    const float* w_ni = (const float*)d_in[12];
    const float* b_ni = (const float*)d_in[13];
    const float* w_fc = (const float*)d_in[14];
    const float* b_fc = (const float*)d_in[15];
    float* out = (float*)d_out;

    char* ws = (char*)d_ws;
    float*    params = (float*)ws;                     // 7.9 MB
    _Float16* gh     = (_Float16*)(ws + (8u << 20));   // 4 MB edge halos
    int*      cnt    = (int*)(ws + (12u << 20));       // 2 KB counters
    _Float16* Wpk    = (_Float16*)(ws + (13u << 20));  // 36 MB packed weights

    prep<<<480, 256, 0, stream>>>(x, b_rh, b_ri, b_uh, b_ui, b_nh, b_ni,
                                  params, cnt);
    prep_w<<<L_, 256, 0, stream>>>(w_rh, w_uh, w_nh, w_ri, w_ui, w_ni, Wpk);

    void* args[] = {
        (void*)&Wpk, (void*)&att, (void*)&params, (void*)&w_fc, (void*)&b_fc,
        (void*)&gh,  (void*)&cnt, (void*)&out,
    };
    hipError_t e = hipLaunchCooperativeKernel((const void*)gru_persist,
                                              dim3(NCH), dim3(512), args, 0, stream);
    if (e != hipSuccess) {
        // 256 blocks at 1 block/CU on 256 CUs: co-resident regardless.
        gru_persist<<<NCH, 512, 0, stream>>>(Wpk, att, params, w_fc, b_fc,
                                             gh, cnt, out);
    }
}

// Round 9
// 214.270 us; speedup vs baseline: 1.2891x; 1.0749x over previous
//
#include <hip/hip_runtime.h>

#define B_ 32
#define T_ 12
#define F_ 4
#define L_ 1024
#define H_ 64
#define NROWS 1920   // 1536 x rows + 6*64 bias rows
#define NCH 256      // chunks (blocks); 4 links per chunk

typedef _Float16 f16x8 __attribute__((ext_vector_type(8)));
typedef float f32x4 __attribute__((ext_vector_type(4)));
typedef unsigned long long u64;

// XCD-chunked swizzle: XCD x owns chunks [32x, 32x+32) = links [128x, 128x+128)
__device__ __forceinline__ int chunk_of_block(int bid) {
    return ((bid & 7) << 5) + (bid >> 3);
}

// ---------------------------------------------------------------------------
// Prep: transpose x [1536 rows][L] and 6 bias arrays [64 rows][L] into
// params[l][NROWS], zero the edge counters.
// ---------------------------------------------------------------------------
__global__ __launch_bounds__(256) void prep(
    const float* __restrict__ x,
    const float* __restrict__ b_rh, const float* __restrict__ b_ri,
    const float* __restrict__ b_uh, const float* __restrict__ b_ui,
    const float* __restrict__ b_nh, const float* __restrict__ b_ni,
    float* __restrict__ params, int* __restrict__ cnt)
{
    const int tid = threadIdx.x;
    const int rt  = blockIdx.x >> 4;   // 30 row tiles
    const int lt  = blockIdx.x & 15;   // 16 link tiles
    __shared__ float lds[64][65];

    if (blockIdx.x == 0 && tid < NCH) {
        __hip_atomic_store(&cnt[tid], 0, __ATOMIC_RELAXED, __HIP_MEMORY_SCOPE_AGENT);
        __hip_atomic_store(&cnt[NCH + tid], 0, __ATOMIC_RELAXED, __HIP_MEMORY_SCOPE_AGENT);
    }

    #pragma unroll
    for (int i = 0; i < 16; ++i) {
        const int e  = i * 256 + tid;
        const int rl = e >> 6, ll = e & 63;
        const int r  = rt * 64 + rl, l = lt * 64 + ll;
        float v;
        if (r < 1536) {
            v = x[(size_t)r * L_ + l];
        } else {
            const int rb = r - 1536;
            const int g  = rb >> 6;
            const float* bp = (g == 0) ? b_rh : (g == 1) ? b_ri : (g == 2) ? b_uh
                            : (g == 3) ? b_ui : (g == 4) ? b_nh : b_ni;
            v = bp[(size_t)(rb & 63) * L_ + l];
        }
        lds[rl][ll] = v;
    }
    __syncthreads();
    #pragma unroll
    for (int i = 0; i < 16; ++i) {
        const int e  = i * 256 + tid;
        const int ll = e >> 6, rl = e & 63;
        params[(size_t)(lt * 64 + ll) * NROWS + rt * 64 + rl] = lds[rl][ll];
    }
}

// ---------------------------------------------------------------------------
// Prep_w: pack all per-link MFMA B fragments (fp16) in consumer-coalesced
// layout Wpk[l][f][lane], f = nt*9 + s with s: 0,1=r ks0/1, 2=r x, 3,4=z ks,
// 5=z x, 6,7=nh ks, 8=nx x. x-frags occupy K rows 0..3 of a K=32 step.
// ---------------------------------------------------------------------------
__global__ __launch_bounds__(256) void prep_w(
    const float* __restrict__ w_rh, const float* __restrict__ w_uh,
    const float* __restrict__ w_nh,
    const float* __restrict__ w_ri, const float* __restrict__ w_ui,
    const float* __restrict__ w_ni, _Float16* __restrict__ Wpk)
{
    const int l  = blockIdx.x;
    const int fq = threadIdx.x >> 6, m = threadIdx.x & 63;
    const int n  = m & 15, kq = m >> 4;
    #pragma unroll
    for (int i = 0; i < 9; ++i) {
        const int f  = i * 4 + fq;          // 0..35
        const int nt = f / 9, s = f % 9;
        const int grp = s / 3, sub = s % 3; // grp 0=r,1=z,2=n
        f16x8 v;
        if (sub < 2) {   // hidden-weight fragment, ks = sub
            const float* wh = (grp == 0) ? w_rh : (grp == 1) ? w_uh : w_nh;
            #pragma unroll
            for (int j = 0; j < 8; ++j)
                v[j] = (_Float16)wh[(size_t)l * 4096
                         + (size_t)(sub * 32 + kq * 8 + j) * 64 + nt * 16 + n];
        } else {         // x-weight fragment (K=32, rows 0..3 live)
            const float* wx = (grp == 0) ? w_ri : (grp == 1) ? w_ui : w_ni;
            #pragma unroll
            for (int j = 0; j < 8; ++j) {
                const int k = kq * 8 + j;
                v[j] = (k < 4) ? (_Float16)wx[(size_t)l * 256 + k * 64 + nt * 16 + n]
                               : (_Float16)0.0f;
            }
        }
        *(f16x8*)(Wpk + (((size_t)l * 36 + f) * 64 + m) * 8) = v;
    }
}

// LDS h buffer: [parity][slot 0..5][b 0..31][k 0..63] fp16, XOR-swizzled.
// slot 0 = left ghost, 1..4 = links, 5 = right ghost.
__device__ __forceinline__ int h_byte(int p, int w, int b, int k) {
    int byte = ((((p * 6 + w) * 32 + b) * 64) + k) * 2;
    return byte ^ ((b & 7) << 4);
}

// ---------------------------------------------------------------------------
// Persistent GRU: 256 blocks (1/CU) x 512 threads (8 waves = 2/SIMD).
// Wave w: link lw = w>>1, output-half nth = w&1 (k columns nth*32..+32).
// Per step: 2 poll threads spin on neighbor counters -> barrier -> ALL
// threads stage the 2 x 4KB ghost halos with ONE parallel u64 atomic load
// each -> barrier -> branch-free LDS compute. Publish unchanged.
// ---------------------------------------------------------------------------
__global__ __launch_bounds__(512, 1) void gru_persist(
    const _Float16* __restrict__ Wpk,
    const float* __restrict__ att,  const float* __restrict__ params,
    const float* __restrict__ w_fc, const float* __restrict__ b_fc,
    _Float16* __restrict__ gh, int* __restrict__ cnt,
    float* __restrict__ out)
{
    const int c    = chunk_of_block(blockIdx.x);
    const int tid  = threadIdx.x;
    const int w    = tid >> 6, lane = tid & 63;
    const int n    = lane & 15, kq = lane >> 4;
    const int lw   = w >> 1, nth = w & 1;
    const int l    = c * 4 + lw;

    __shared__ __align__(16) _Float16 hbuf[2 * 6 * 32 * 64];  // 48 KB
    __shared__ __align__(16) float    xs[4][1536];            // 24 KB
    __shared__ float psum[4][2][B_];                          // 1 KB (FC head)

    // ---- stage this link's x into LDS (wave-pair cooperative, coalesced)
    const float* prow = params + (size_t)l * NROWS;
    {
        const float4* src = (const float4*)prow;
        float4* dst = (float4*)xs[lw];
        const int sub = tid & 127;     // position within the wave pair
        #pragma unroll
        for (int i = 0; i < 3; ++i) dst[sub + i * 128] = src[sub + i * 128];
    }
    // ---- zero ghost slots (NaN-safe for boundary chunks; 2048 u64)
    {
        char* hb = (char*)hbuf;
        #pragma unroll
        for (int i = 0; i < 4; ++i) {
            const int idx = i * 512 + tid;          // 0..2047
            const int p = idx >> 10, sl = (idx >> 9) & 1;
            const int b = (idx >> 4) & 31, kk = idx & 15;
            *(u64*)(hb + h_byte(p, sl * 5, b, kk * 4)) = 0ull;
        }
    }

    // ---- per-lane persistent constants (disjoint per nth; all coalesced)
    f16x8 bw[2][9];   // [q = local nt][s]
    {
        const f16x8* wp = (const f16x8*)Wpk + (size_t)l * 36 * 64;
        #pragma unroll
        for (int q = 0; q < 2; ++q)
            #pragma unroll
            for (int s = 0; s < 9; ++s)
                bw[q][s] = wp[((nth * 2 + q) * 9 + s) * 64 + lane];
    }
    float brv[2], bzv[2], bnhv[2], bniv[2], wfcv[2];
    #pragma unroll
    for (int q = 0; q < 2; ++q) {
        const int ko = (nth * 2 + q) * 16 + n;
        brv[q]  = prow[1536 + 0 * 64 + ko] + prow[1536 + 1 * 64 + ko];
        bzv[q]  = prow[1536 + 2 * 64 + ko] + prow[1536 + 3 * 64 + ko];
        bnhv[q] = prow[1536 + 4 * 64 + ko];
        bniv[q] = prow[1536 + 5 * 64 + ko];
        wfcv[q] = w_fc[(size_t)l * H_ + ko];
    }
    const _Float16 ach = (_Float16)att[(size_t)l * L_ + l];
    const _Float16 alh = (l > 0)      ? (_Float16)att[(size_t)l * L_ + l - 1] : (_Float16)0.0f;
    const _Float16 arh = (l < L_ - 1) ? (_Float16)att[(size_t)l * L_ + l + 1] : (_Float16)0.0f;

    __syncthreads();   // xs + ghost-zero ready

    float hvv[2][2][4] = {};   // [mt][q][r]

    #pragma unroll 1
    for (int t = 0; t < T_; ++t) {
        f32x4 ar[2][2] = {}, az[2][2] = {}, anh[2][2] = {}, anx[2][2] = {};
        if (t > 0) {
            // poll threads (waves 0 and 7); everyone else proceeds to barrier
            if (tid == 0 && c > 0)
                while (__hip_atomic_load(&cnt[NCH + c - 1], __ATOMIC_RELAXED,
                                         __HIP_MEMORY_SCOPE_AGENT) < 2 * t)
                    __builtin_amdgcn_s_sleep(1);
            if (tid == 511 && c < NCH - 1)
                while (__hip_atomic_load(&cnt[c + 1], __ATOMIC_RELAXED,
                                         __HIP_MEMORY_SCOPE_AGENT) < 2 * t)
                    __builtin_amdgcn_s_sleep(1);
            __syncthreads();   // polls confirmed for the whole block

            const int p = (t - 1) & 1;
            char* hbw_ = (char*)hbuf;
            // ---- stage ghosts: 1 u64 atomic load per thread per side
            {
                const int b = tid >> 4, kk = tid & 15;
                if (c > 0) {
                    const u64* s64 = (const u64*)(gh +
                        ((((size_t)p * NCH + (c - 1)) * 2 + 1) * 2048));
                    const u64 v = __hip_atomic_load(s64 + tid, __ATOMIC_RELAXED,
                                                    __HIP_MEMORY_SCOPE_AGENT);
                    *(u64*)(hbw_ + h_byte(p, 0, b, kk * 4)) = v;
                }
                if (c < NCH - 1) {
                    const u64* s64 = (const u64*)(gh +
                        ((((size_t)p * NCH + (c + 1)) * 2 + 0) * 2048));
                    const u64 v = __hip_atomic_load(s64 + tid, __ATOMIC_RELAXED,
                                                    __HIP_MEMORY_SCOPE_AGENT);
                    *(u64*)(hbw_ + h_byte(p, 5, b, kk * 4)) = v;
                }
            }
            __syncthreads();   // ghosts in LDS

            const char* hb = (const char*)hbuf;
            f16x8 af[2][2];   // [mt][ks], full k range; branch-free LDS reads
            #pragma unroll
            for (int mt = 0; mt < 2; ++mt) {
                #pragma unroll
                for (int ks = 0; ks < 2; ++ks) {
                    const int b  = mt * 16 + n;
                    const int k0 = ks * 32 + kq * 8;
                    const f16x8 hs = *(const f16x8*)(hb + h_byte(p, lw + 1, b, k0));
                    const f16x8 hl = *(const f16x8*)(hb + h_byte(p, lw,     b, k0));
                    const f16x8 hr = *(const f16x8*)(hb + h_byte(p, lw + 2, b, k0));
                    af[mt][ks] = ach * hs + alh * hl + arh * hr;   // packed f16 FMA
                }
            }
            #pragma unroll
            for (int q = 0; q < 2; ++q)
                #pragma unroll
                for (int mt = 0; mt < 2; ++mt) {
                    ar[mt][q]  = __builtin_amdgcn_mfma_f32_16x16x32_f16(af[mt][0], bw[q][0], ar[mt][q],  0,0,0);
                    ar[mt][q]  = __builtin_amdgcn_mfma_f32_16x16x32_f16(af[mt][1], bw[q][1], ar[mt][q],  0,0,0);
                    az[mt][q]  = __builtin_amdgcn_mfma_f32_16x16x32_f16(af[mt][0], bw[q][3], az[mt][q],  0,0,0);
                    az[mt][q]  = __builtin_amdgcn_mfma_f32_16x16x32_f16(af[mt][1], bw[q][4], az[mt][q],  0,0,0);
                    anh[mt][q] = __builtin_amdgcn_mfma_f32_16x16x32_f16(af[mt][0], bw[q][6], anh[mt][q], 0,0,0);
                    anh[mt][q] = __builtin_amdgcn_mfma_f32_16x16x32_f16(af[mt][1], bw[q][7], anh[mt][q], 0,0,0);
                }
        }

        // ---- x contribution via MFMA (K rows 0..3 of a K=32 step)
        {
            f16x8 ax[2] = {};
            #pragma unroll
            for (int mt = 0; mt < 2; ++mt)
                if (kq == 0) {
                    const float4 xb = *(const float4*)&xs[lw][(mt * 16 + n) * 48 + t * 4];
                    ax[mt][0] = (_Float16)xb.x; ax[mt][1] = (_Float16)xb.y;
                    ax[mt][2] = (_Float16)xb.z; ax[mt][3] = (_Float16)xb.w;
                }
            #pragma unroll
            for (int q = 0; q < 2; ++q)
                #pragma unroll
                for (int mt = 0; mt < 2; ++mt) {
                    ar[mt][q]  = __builtin_amdgcn_mfma_f32_16x16x32_f16(ax[mt], bw[q][2], ar[mt][q],  0,0,0);
                    az[mt][q]  = __builtin_amdgcn_mfma_f32_16x16x32_f16(ax[mt], bw[q][5], az[mt][q],  0,0,0);
                    anx[mt][q] = __builtin_amdgcn_mfma_f32_16x16x32_f16(ax[mt], bw[q][8], anx[mt][q], 0,0,0);
                }
        }

        // ---- gates + state update (f32)
        #pragma unroll
        for (int mt = 0; mt < 2; ++mt)
            #pragma unroll
            for (int q = 0; q < 2; ++q)
                #pragma unroll
                for (int r = 0; r < 4; ++r) {
                    const float pre_r = ar[mt][q][r] + brv[q];
                    const float pre_z = az[mt][q][r] + bzv[q];
                    const float rg = 1.0f / (1.0f + __expf(-pre_r));
                    const float zg = 1.0f / (1.0f + __expf(-pre_z));
                    float npre = anx[mt][q][r] + bniv[q] + rg * (anh[mt][q][r] + bnhv[q]);
                    npre = fminf(fmaxf(npre, -15.0f), 15.0f);
                    const float e2 = __expf(2.0f * npre);
                    const float nn = (e2 - 1.0f) / (e2 + 1.0f);
                    hvv[mt][q][r] = (1.0f - zg) * nn + zg * hvv[mt][q][r];
                }

        if (t < T_ - 1) {
            const int qp = t & 1;
            char* hb = (char*)hbuf;
            #pragma unroll
            for (int mt = 0; mt < 2; ++mt)
                #pragma unroll
                for (int q = 0; q < 2; ++q)
                    #pragma unroll
                    for (int r = 0; r < 4; ++r)
                        *(_Float16*)(hb + h_byte(qp, lw + 1, mt * 16 + kq * 4 + r,
                                                 (nth * 2 + q) * 16 + n))
                            = (_Float16)hvv[mt][q][r];
            // edge waves: push own k-half halo (all b) + RELEASE counter bump
            if (lw == 0 && c > 0) {
                u64* ge = (u64*)(gh + (((size_t)qp * NCH + c) * 2 + 0) * 2048);
                #pragma unroll
                for (int i = 0; i < 4; ++i) {
                    const int idx2 = lane + i * 64;          // 0..255
                    const int b = idx2 >> 3, kk = idx2 & 7;  // k-half: 8 u64 per b
                    const u64 v = *(const u64*)(hb + h_byte(qp, 1, b, nth * 32 + kk * 4));
                    __hip_atomic_store(ge + b * 16 + nth * 8 + kk, v,
                                       __ATOMIC_RELAXED, __HIP_MEMORY_SCOPE_AGENT);
                }
                if (lane == 0)
                    __hip_atomic_fetch_add(&cnt[c], 1, __ATOMIC_RELEASE,
                                           __HIP_MEMORY_SCOPE_AGENT);
            }
            if (lw == 3 && c < NCH - 1) {
                u64* ge = (u64*)(gh + (((size_t)qp * NCH + c) * 2 + 1) * 2048);
                #pragma unroll
                for (int i = 0; i < 4; ++i) {
                    const int idx2 = lane + i * 64;
                    const int b = idx2 >> 3, kk = idx2 & 7;
                    const u64 v = *(const u64*)(hb + h_byte(qp, 4, b, nth * 32 + kk * 4));
                    __hip_atomic_store(ge + b * 16 + nth * 8 + kk, v,
                                       __ATOMIC_RELAXED, __HIP_MEMORY_SCOPE_AGENT);
                }
                if (lane == 0)
                    __hip_atomic_fetch_add(&cnt[NCH + c], 1, __ATOMIC_RELEASE,
                                           __HIP_MEMORY_SCOPE_AGENT);
            }
            __syncthreads();   // hbuf parity qp visible to sibling waves
        } else {
            // FC head: partial over own k-half, combine nth pair via LDS
            #pragma unroll
            for (int mt = 0; mt < 2; ++mt)
                #pragma unroll
                for (int r = 0; r < 4; ++r) {
                    float s = hvv[mt][0][r] * wfcv[0] + hvv[mt][1][r] * wfcv[1];
                    s += __shfl_xor(s, 1, 64);
                    s += __shfl_xor(s, 2, 64);
                    s += __shfl_xor(s, 4, 64);
                    s += __shfl_xor(s, 8, 64);
                    if (n == 0) psum[lw][nth][mt * 16 + kq * 4 + r] = s;
                }
            __syncthreads();
            if (tid < 128) {
                const int lw2 = tid >> 5, b = tid & 31;
                const int l2 = c * 4 + lw2;
                out[(size_t)b * L_ + l2] =
                    psum[lw2][0][b] + psum[lw2][1][b] + b_fc[l2];
            }
        }
    }
}

extern "C" void kernel_launch(void* const* d_in, const int* in_sizes, int n_in,
                              void* d_out, int out_size, void* d_ws, size_t ws_size,
                              hipStream_t stream) {
    const float* x    = (const float*)d_in[0];
    const float* att  = (const float*)d_in[1];
    const float* w_rh = (const float*)d_in[2];
    const float* b_rh = (const float*)d_in[3];
    const float* w_ri = (const float*)d_in[4];
    const float* b_ri = (const float*)d_in[5];
    const float* w_uh = (const float*)d_in[6];
    const float* b_uh = (const float*)d_in[7];
    const float* w_ui = (const float*)d_in[8];
    const float* b_ui = (const float*)d_in[9];
    const float* w_nh = (const float*)d_in[10];
    const float* b_nh = (const float*)d_in[11];
    const float* w_ni = (const float*)d_in[12];
    const float* b_ni = (const float*)d_in[13];
    const float* w_fc = (const float*)d_in[14];
    const float* b_fc = (const float*)d_in[15];
    float* out = (float*)d_out;

    char* ws = (char*)d_ws;
    float*    params = (float*)ws;                     // 7.9 MB
    _Float16* gh     = (_Float16*)(ws + (8u << 20));   // 4 MB edge halos
    int*      cnt    = (int*)(ws + (12u << 20));       // 2 KB counters
    _Float16* Wpk    = (_Float16*)(ws + (13u << 20));  // 36 MB packed weights

    prep<<<480, 256, 0, stream>>>(x, b_rh, b_ri, b_uh, b_ui, b_nh, b_ni,
                                  params, cnt);
    prep_w<<<L_, 256, 0, stream>>>(w_rh, w_uh, w_nh, w_ri, w_ui, w_ni, Wpk);

    void* args[] = {
        (void*)&Wpk, (void*)&att, (void*)&params, (void*)&w_fc, (void*)&b_fc,
        (void*)&gh,  (void*)&cnt, (void*)&out,
    };
    hipError_t e = hipLaunchCooperativeKernel((const void*)gru_persist,
                                              dim3(NCH), dim3(512), args, 0, stream);
    if (e != hipSuccess) {
        // 256 blocks at 1 block/CU on 256 CUs: co-resident regardless.
        gru_persist<<<NCH, 512, 0, stream>>>(Wpk, att, params, w_fc, b_fc,
                                             gh, cnt, out);
    }
}

// Round 10
// 189.509 us; speedup vs baseline: 1.4576x; 1.1307x over previous
//
#include <hip/hip_runtime.h>

#define B_ 32
#define T_ 12
#define F_ 4
#define L_ 1024
#define H_ 64
#define NROWS 1920   // 1536 x rows + 6*64 bias rows
#define NCH 256      // chunks (blocks); 4 links per chunk
#define CPAD 32      // u32 per counter slot (128 B = 1 LLC line)

typedef _Float16 f16x8 __attribute__((ext_vector_type(8)));
typedef float f32x4 __attribute__((ext_vector_type(4)));
typedef unsigned long long u64;

// XCD-chunked swizzle: XCD x owns chunks [32x, 32x+32) = links [128x, 128x+128)
__device__ __forceinline__ int chunk_of_block(int bid) {
    return ((bid & 7) << 5) + (bid >> 3);
}

// counter slot: [chunk][side (0=left edge,1=right edge)][nth]
__device__ __forceinline__ int cslot(int c, int side, int nth) {
    return ((c * 4) + side * 2 + nth) * CPAD;
}

// ---------------------------------------------------------------------------
// Prep: transpose x [1536 rows][L] and 6 bias arrays [64 rows][L] into
// params[l][NROWS], zero the (padded) edge counters.
// ---------------------------------------------------------------------------
__global__ __launch_bounds__(256) void prep(
    const float* __restrict__ x,
    const float* __restrict__ b_rh, const float* __restrict__ b_ri,
    const float* __restrict__ b_uh, const float* __restrict__ b_ui,
    const float* __restrict__ b_nh, const float* __restrict__ b_ni,
    float* __restrict__ params, int* __restrict__ cnt)
{
    const int tid = threadIdx.x;
    const int rt  = blockIdx.x >> 4;   // 30 row tiles
    const int lt  = blockIdx.x & 15;   // 16 link tiles
    __shared__ float lds[64][65];

    if (blockIdx.x == 0)
        for (int i = tid; i < NCH * 4; i += 256)
            __hip_atomic_store(&cnt[i * CPAD], 0, __ATOMIC_RELAXED,
                               __HIP_MEMORY_SCOPE_AGENT);

    #pragma unroll
    for (int i = 0; i < 16; ++i) {
        const int e  = i * 256 + tid;
        const int rl = e >> 6, ll = e & 63;
        const int r  = rt * 64 + rl, l = lt * 64 + ll;
        float v;
        if (r < 1536) {
            v = x[(size_t)r * L_ + l];
        } else {
            const int rb = r - 1536;
            const int g  = rb >> 6;
            const float* bp = (g == 0) ? b_rh : (g == 1) ? b_ri : (g == 2) ? b_uh
                            : (g == 3) ? b_ui : (g == 4) ? b_nh : b_ni;
            v = bp[(size_t)(rb & 63) * L_ + l];
        }
        lds[rl][ll] = v;
    }
    __syncthreads();
    #pragma unroll
    for (int i = 0; i < 16; ++i) {
        const int e  = i * 256 + tid;
        const int ll = e >> 6, rl = e & 63;
        params[(size_t)(lt * 64 + ll) * NROWS + rt * 64 + rl] = lds[rl][ll];
    }
}

// ---------------------------------------------------------------------------
// Prep_w: pack all per-link MFMA B fragments (fp16) in consumer-coalesced
// layout Wpk[l][f][lane], f = nt*9 + s with s: 0,1=r ks0/1, 2=r x, 3,4=z ks,
// 5=z x, 6,7=nh ks, 8=nx x. x-frags occupy K rows 0..3 of a K=32 step.
// ---------------------------------------------------------------------------
__global__ __launch_bounds__(256) void prep_w(
    const float* __restrict__ w_rh, const float* __restrict__ w_uh,
    const float* __restrict__ w_nh,
    const float* __restrict__ w_ri, const float* __restrict__ w_ui,
    const float* __restrict__ w_ni, _Float16* __restrict__ Wpk)
{
    const int l  = blockIdx.x;
    const int fq = threadIdx.x >> 6, m = threadIdx.x & 63;
    const int n  = m & 15, kq = m >> 4;
    #pragma unroll
    for (int i = 0; i < 9; ++i) {
        const int f  = i * 4 + fq;          // 0..35
        const int nt = f / 9, s = f % 9;
        const int grp = s / 3, sub = s % 3; // grp 0=r,1=z,2=n
        f16x8 v;
        if (sub < 2) {   // hidden-weight fragment, ks = sub
            const float* wh = (grp == 0) ? w_rh : (grp == 1) ? w_uh : w_nh;
            #pragma unroll
            for (int j = 0; j < 8; ++j)
                v[j] = (_Float16)wh[(size_t)l * 4096
                         + (size_t)(sub * 32 + kq * 8 + j) * 64 + nt * 16 + n];
        } else {         // x-weight fragment (K=32, rows 0..3 live)
            const float* wx = (grp == 0) ? w_ri : (grp == 1) ? w_ui : w_ni;
            #pragma unroll
            for (int j = 0; j < 8; ++j) {
                const int k = kq * 8 + j;
                v[j] = (k < 4) ? (_Float16)wx[(size_t)l * 256 + k * 64 + nt * 16 + n]
                               : (_Float16)0.0f;
            }
        }
        *(f16x8*)(Wpk + (((size_t)l * 36 + f) * 64 + m) * 8) = v;
    }
}

// LDS h buffer: [parity][slot 0..5][b 0..31][k 0..63] fp16, XOR-swizzled.
// slot 0 = left ghost, 1..4 = links, 5 = right ghost.
__device__ __forceinline__ int h_byte(int p, int w, int b, int k) {
    int byte = ((((p * 6 + w) * 32 + b) * 64) + k) * 2;
    return byte ^ ((b & 7) << 4);
}

// ---------------------------------------------------------------------------
// Persistent GRU: 256 blocks (1/CU) x 512 threads (8 waves = 2/SIMD).
// Wave w: link lw = w>>1, output-half nth = w&1 (k columns nth*32..+32).
// Per step: 4 poll threads (4 distinct waves) spin on their own padded
// counter line -> barrier -> ALL threads stage the 2 x 4KB ghost halos with
// one parallel u64 atomic load each -> barrier -> branch-free LDS compute.
// Publish: per-wave halo stores + single plain RELEASE store (no RMW) to a
// dedicated 128-B-padded counter line.
// ---------------------------------------------------------------------------
__global__ __launch_bounds__(512, 1) void gru_persist(
    const _Float16* __restrict__ Wpk,
    const float* __restrict__ att,  const float* __restrict__ params,
    const float* __restrict__ w_fc, const float* __restrict__ b_fc,
    _Float16* __restrict__ gh, int* __restrict__ cnt,
    float* __restrict__ out)
{
    const int c    = chunk_of_block(blockIdx.x);
    const int tid  = threadIdx.x;
    const int w    = tid >> 6, lane = tid & 63;
    const int n    = lane & 15, kq = lane >> 4;
    const int lw   = w >> 1, nth = w & 1;
    const int l    = c * 4 + lw;

    __shared__ __align__(16) _Float16 hbuf[2 * 6 * 32 * 64];  // 48 KB
    __shared__ __align__(16) float    xs[4][1536];            // 24 KB
    __shared__ float psum[4][2][B_];                          // 1 KB (FC head)

    // ---- stage this link's x into LDS (wave-pair cooperative, coalesced)
    const float* prow = params + (size_t)l * NROWS;
    {
        const float4* src = (const float4*)prow;
        float4* dst = (float4*)xs[lw];
        const int sub = tid & 127;     // position within the wave pair
        #pragma unroll
        for (int i = 0; i < 3; ++i) dst[sub + i * 128] = src[sub + i * 128];
    }
    // ---- zero ghost slots (NaN-safe for boundary chunks; 2048 u64)
    {
        char* hb = (char*)hbuf;
        #pragma unroll
        for (int i = 0; i < 4; ++i) {
            const int idx = i * 512 + tid;          // 0..2047
            const int p = idx >> 10, sl = (idx >> 9) & 1;
            const int b = (idx >> 4) & 31, kk = idx & 15;
            *(u64*)(hb + h_byte(p, sl * 5, b, kk * 4)) = 0ull;
        }
    }

    // ---- per-lane persistent constants (disjoint per nth; all coalesced)
    f16x8 bw[2][9];   // [q = local nt][s]
    {
        const f16x8* wp = (const f16x8*)Wpk + (size_t)l * 36 * 64;
        #pragma unroll
        for (int q = 0; q < 2; ++q)
            #pragma unroll
            for (int s = 0; s < 9; ++s)
                bw[q][s] = wp[((nth * 2 + q) * 9 + s) * 64 + lane];
    }
    float brv[2], bzv[2], bnhv[2], bniv[2], wfcv[2];
    #pragma unroll
    for (int q = 0; q < 2; ++q) {
        const int ko = (nth * 2 + q) * 16 + n;
        brv[q]  = prow[1536 + 0 * 64 + ko] + prow[1536 + 1 * 64 + ko];
        bzv[q]  = prow[1536 + 2 * 64 + ko] + prow[1536 + 3 * 64 + ko];
        bnhv[q] = prow[1536 + 4 * 64 + ko];
        bniv[q] = prow[1536 + 5 * 64 + ko];
        wfcv[q] = w_fc[(size_t)l * H_ + ko];
    }
    const _Float16 ach = (_Float16)att[(size_t)l * L_ + l];
    const _Float16 alh = (l > 0)      ? (_Float16)att[(size_t)l * L_ + l - 1] : (_Float16)0.0f;
    const _Float16 arh = (l < L_ - 1) ? (_Float16)att[(size_t)l * L_ + l + 1] : (_Float16)0.0f;

    __syncthreads();   // xs + ghost-zero ready

    float hvv[2][2][4] = {};   // [mt][q][r]

    #pragma unroll 1
    for (int t = 0; t < T_; ++t) {
        f32x4 ar[2][2] = {}, az[2][2] = {}, anh[2][2] = {}, anx[2][2] = {};
        if (t > 0) {
            // 4 poll threads in 4 distinct waves; each owns one padded line
            if (c > 0) {
                if (tid == 0)
                    while (__hip_atomic_load(&cnt[cslot(c - 1, 1, 0)], __ATOMIC_RELAXED,
                                             __HIP_MEMORY_SCOPE_AGENT) < t)
                        __builtin_amdgcn_s_sleep(1);
                if (tid == 64)
                    while (__hip_atomic_load(&cnt[cslot(c - 1, 1, 1)], __ATOMIC_RELAXED,
                                             __HIP_MEMORY_SCOPE_AGENT) < t)
                        __builtin_amdgcn_s_sleep(1);
            }
            if (c < NCH - 1) {
                if (tid == 384)
                    while (__hip_atomic_load(&cnt[cslot(c + 1, 0, 0)], __ATOMIC_RELAXED,
                                             __HIP_MEMORY_SCOPE_AGENT) < t)
                        __builtin_amdgcn_s_sleep(1);
                if (tid == 511)
                    while (__hip_atomic_load(&cnt[cslot(c + 1, 0, 1)], __ATOMIC_RELAXED,
                                             __HIP_MEMORY_SCOPE_AGENT) < t)
                        __builtin_amdgcn_s_sleep(1);
            }
            __syncthreads();   // polls confirmed for the whole block

            const int p = (t - 1) & 1;
            char* hbw_ = (char*)hbuf;
            // ---- stage ghosts: 1 u64 atomic load per thread per side
            {
                const int b = tid >> 4, kk = tid & 15;
                if (c > 0) {
                    const u64* s64 = (const u64*)(gh +
                        ((((size_t)p * NCH + (c - 1)) * 2 + 1) * 2048));
                    const u64 v = __hip_atomic_load(s64 + tid, __ATOMIC_RELAXED,
                                                    __HIP_MEMORY_SCOPE_AGENT);
                    *(u64*)(hbw_ + h_byte(p, 0, b, kk * 4)) = v;
                }
                if (c < NCH - 1) {
                    const u64* s64 = (const u64*)(gh +
                        ((((size_t)p * NCH + (c + 1)) * 2 + 0) * 2048));
                    const u64 v = __hip_atomic_load(s64 + tid, __ATOMIC_RELAXED,
                                                    __HIP_MEMORY_SCOPE_AGENT);
                    *(u64*)(hbw_ + h_byte(p, 5, b, kk * 4)) = v;
                }
            }
            __syncthreads();   // ghosts in LDS

            const char* hb = (const char*)hbuf;
            f16x8 af[2][2];   // [mt][ks], full k range; branch-free LDS reads
            #pragma unroll
            for (int mt = 0; mt < 2; ++mt) {
                #pragma unroll
                for (int ks = 0; ks < 2; ++ks) {
                    const int b  = mt * 16 + n;
                    const int k0 = ks * 32 + kq * 8;
                    const f16x8 hs = *(const f16x8*)(hb + h_byte(p, lw + 1, b, k0));
                    const f16x8 hl = *(const f16x8*)(hb + h_byte(p, lw,     b, k0));
                    const f16x8 hr = *(const f16x8*)(hb + h_byte(p, lw + 2, b, k0));
                    af[mt][ks] = ach * hs + alh * hl + arh * hr;   // packed f16 FMA
                }
            }
            #pragma unroll
            for (int q = 0; q < 2; ++q)
                #pragma unroll
                for (int mt = 0; mt < 2; ++mt) {
                    ar[mt][q]  = __builtin_amdgcn_mfma_f32_16x16x32_f16(af[mt][0], bw[q][0], ar[mt][q],  0,0,0);
                    ar[mt][q]  = __builtin_amdgcn_mfma_f32_16x16x32_f16(af[mt][1], bw[q][1], ar[mt][q],  0,0,0);
                    az[mt][q]  = __builtin_amdgcn_mfma_f32_16x16x32_f16(af[mt][0], bw[q][3], az[mt][q],  0,0,0);
                    az[mt][q]  = __builtin_amdgcn_mfma_f32_16x16x32_f16(af[mt][1], bw[q][4], az[mt][q],  0,0,0);
                    anh[mt][q] = __builtin_amdgcn_mfma_f32_16x16x32_f16(af[mt][0], bw[q][6], anh[mt][q], 0,0,0);
                    anh[mt][q] = __builtin_amdgcn_mfma_f32_16x16x32_f16(af[mt][1], bw[q][7], anh[mt][q], 0,0,0);
                }
        }

        // ---- x contribution via MFMA (K rows 0..3 of a K=32 step)
        {
            f16x8 ax[2] = {};
            #pragma unroll
            for (int mt = 0; mt < 2; ++mt)
                if (kq == 0) {
                    const float4 xb = *(const float4*)&xs[lw][(mt * 16 + n) * 48 + t * 4];
                    ax[mt][0] = (_Float16)xb.x; ax[mt][1] = (_Float16)xb.y;
                    ax[mt][2] = (_Float16)xb.z; ax[mt][3] = (_Float16)xb.w;
                }
            #pragma unroll
            for (int q = 0; q < 2; ++q)
                #pragma unroll
                for (int mt = 0; mt < 2; ++mt) {
                    ar[mt][q]  = __builtin_amdgcn_mfma_f32_16x16x32_f16(ax[mt], bw[q][2], ar[mt][q],  0,0,0);
                    az[mt][q]  = __builtin_amdgcn_mfma_f32_16x16x32_f16(ax[mt], bw[q][5], az[mt][q],  0,0,0);
                    anx[mt][q] = __builtin_amdgcn_mfma_f32_16x16x32_f16(ax[mt], bw[q][8], anx[mt][q], 0,0,0);
                }
        }

        // ---- gates + state update (f32)
        #pragma unroll
        for (int mt = 0; mt < 2; ++mt)
            #pragma unroll
            for (int q = 0; q < 2; ++q)
                #pragma unroll
                for (int r = 0; r < 4; ++r) {
                    const float pre_r = ar[mt][q][r] + brv[q];
                    const float pre_z = az[mt][q][r] + bzv[q];
                    const float rg = 1.0f / (1.0f + __expf(-pre_r));
                    const float zg = 1.0f / (1.0f + __expf(-pre_z));
                    float npre = anx[mt][q][r] + bniv[q] + rg * (anh[mt][q][r] + bnhv[q]);
                    npre = fminf(fmaxf(npre, -15.0f), 15.0f);
                    const float e2 = __expf(2.0f * npre);
                    const float nn = (e2 - 1.0f) / (e2 + 1.0f);
                    hvv[mt][q][r] = (1.0f - zg) * nn + zg * hvv[mt][q][r];
                }

        if (t < T_ - 1) {
            const int qp = t & 1;
            char* hb = (char*)hbuf;
            #pragma unroll
            for (int mt = 0; mt < 2; ++mt)
                #pragma unroll
                for (int q = 0; q < 2; ++q)
                    #pragma unroll
                    for (int r = 0; r < 4; ++r)
                        *(_Float16*)(hb + h_byte(qp, lw + 1, mt * 16 + kq * 4 + r,
                                                 (nth * 2 + q) * 16 + n))
                            = (_Float16)hvv[mt][q][r];
            // edge waves: push own k-half halo (all b), then ONE plain
            // RELEASE store (t+1) to this wave's dedicated counter line.
            if (lw == 0 && c > 0) {
                u64* ge = (u64*)(gh + (((size_t)qp * NCH + c) * 2 + 0) * 2048);
                #pragma unroll
                for (int i = 0; i < 4; ++i) {
                    const int idx2 = lane + i * 64;          // 0..255
                    const int b = idx2 >> 3, kk = idx2 & 7;  // k-half: 8 u64 per b
                    const u64 v = *(const u64*)(hb + h_byte(qp, 1, b, nth * 32 + kk * 4));
                    __hip_atomic_store(ge + b * 16 + nth * 8 + kk, v,
                                       __ATOMIC_RELAXED, __HIP_MEMORY_SCOPE_AGENT);
                }
                if (lane == 0)
                    __hip_atomic_store(&cnt[cslot(c, 0, nth)], t + 1,
                                       __ATOMIC_RELEASE, __HIP_MEMORY_SCOPE_AGENT);
            }
            if (lw == 3 && c < NCH - 1) {
                u64* ge = (u64*)(gh + (((size_t)qp * NCH + c) * 2 + 1) * 2048);
                #pragma unroll
                for (int i = 0; i < 4; ++i) {
                    const int idx2 = lane + i * 64;
                    const int b = idx2 >> 3, kk = idx2 & 7;
                    const u64 v = *(const u64*)(hb + h_byte(qp, 4, b, nth * 32 + kk * 4));
                    __hip_atomic_store(ge + b * 16 + nth * 8 + kk, v,
                                       __ATOMIC_RELAXED, __HIP_MEMORY_SCOPE_AGENT);
                }
                if (lane == 0)
                    __hip_atomic_store(&cnt[cslot(c, 1, nth)], t + 1,
                                       __ATOMIC_RELEASE, __HIP_MEMORY_SCOPE_AGENT);
            }
            __syncthreads();   // hbuf parity qp visible to sibling waves
        } else {
            // FC head: partial over own k-half, combine nth pair via LDS
            #pragma unroll
            for (int mt = 0; mt < 2; ++mt)
                #pragma unroll
                for (int r = 0; r < 4; ++r) {
                    float s = hvv[mt][0][r] * wfcv[0] + hvv[mt][1][r] * wfcv[1];
                    s += __shfl_xor(s, 1, 64);
                    s += __shfl_xor(s, 2, 64);
                    s += __shfl_xor(s, 4, 64);
                    s += __shfl_xor(s, 8, 64);
                    if (n == 0) psum[lw][nth][mt * 16 + kq * 4 + r] = s;
                }
            __syncthreads();
            if (tid < 128) {
                const int lw2 = tid >> 5, b = tid & 31;
                const int l2 = c * 4 + lw2;
                out[(size_t)b * L_ + l2] =
                    psum[lw2][0][b] + psum[lw2][1][b] + b_fc[l2];
            }
        }
    }
}

extern "C" void kernel_launch(void* const* d_in, const int* in_sizes, int n_in,
                              void* d_out, int out_size, void* d_ws, size_t ws_size,
                              hipStream_t stream) {
    const float* x    = (const float*)d_in[0];
    const float* att  = (const float*)d_in[1];
    const float* w_rh = (const float*)d_in[2];
    const float* b_rh = (const float*)d_in[3];
    const float* w_ri = (const float*)d_in[4];
    const float* b_ri = (const float*)d_in[5];
    const float* w_uh = (const float*)d_in[6];
    const float* b_uh = (const float*)d_in[7];
    const float* w_ui = (const float*)d_in[8];
    const float* b_ui = (const float*)d_in[9];
    const float* w_nh = (const float*)d_in[10];
    const float* b_nh = (const float*)d_in[11];
    const float* w_ni = (const float*)d_in[12];
    const float* b_ni = (const float*)d_in[13];
    const float* w_fc = (const float*)d_in[14];
    const float* b_fc = (const float*)d_in[15];
    float* out = (float*)d_out;

    char* ws = (char*)d_ws;
    float*    params = (float*)ws;                     // 7.9 MB
    _Float16* gh     = (_Float16*)(ws + (8u << 20));   // 4 MB edge halos
    int*      cnt    = (int*)(ws + (12u << 20));       // 128 KB padded counters
    _Float16* Wpk    = (_Float16*)(ws + (13u << 20));  // 36 MB packed weights

    prep<<<480, 256, 0, stream>>>(x, b_rh, b_ri, b_uh, b_ui, b_nh, b_ni,
                                  params, cnt);
    prep_w<<<L_, 256, 0, stream>>>(w_rh, w_uh, w_nh, w_ri, w_ui, w_ni, Wpk);

    void* args[] = {
        (void*)&Wpk, (void*)&att, (void*)&params, (void*)&w_fc, (void*)&b_fc,
        (void*)&gh,  (void*)&cnt, (void*)&out,
    };
    hipError_t e = hipLaunchCooperativeKernel((const void*)gru_persist,
                                              dim3(NCH), dim3(512), args, 0, stream);
    if (e != hipSuccess) {
        // 256 blocks at 1 block/CU on 256 CUs: co-resident regardless.
        gru_persist<<<NCH, 512, 0, stream>>>(Wpk, att, params, w_fc, b_fc,
                                             gh, cnt, out);
    }
}